// Round 10
// baseline (149.233 us; speedup 1.0000x reference)
//
#include <hip/hip_runtime.h>
#include <math.h>

#define V_NUM 6890
#define NJ 24
#define KTOT 217            // 10 betas + 207 pose_map
#define KP 256              // padded K (multiple of 64)
#define M_DIM (V_NUM * 3)   // 20670
#define MPAD 20736          // 162 * 128
#define VPAD 6912           // 27 * 256

typedef __attribute__((ext_vector_type(8))) short bf16x8;
typedef __attribute__((ext_vector_type(4))) float f32x4;

__constant__ int c_parents[NJ] = {-1,0,0,0,1,2,3,4,5,6,7,8,9,9,9,12,13,14,16,17,18,19,20,21};

__device__ __forceinline__ unsigned short f2bf(float x) {
  union { float f; unsigned int u; } v; v.f = x;
  unsigned int r = v.u + 0x7fffu + ((v.u >> 16) & 1u);
  return (unsigned short)(r >> 16);
}

#define GLOBAL_AS __attribute__((address_space(1)))
#define LDS_AS __attribute__((address_space(3)))
__device__ __forceinline__ void gl_lds16(const void* g, void* l) {
  __builtin_amdgcn_global_load_lds((const GLOBAL_AS unsigned int*)g,
                                   (LDS_AS unsigned int*)l, 16, 0, 0);
}

// ---------------- Kernel A: J_regressor fold, one output scalar per block ----------------
__global__ __launch_bounds__(256) void k_regress2(
    const float* __restrict__ JR, const float* __restrict__ SD,
    const float* __restrict__ VT, float* __restrict__ JS, float* __restrict__ Jt) {
  int j = blockIdx.x;
  int q = blockIdx.y;
  int tid = threadIdx.x;
  float part = 0.f;
  const float* jr = JR + (size_t)j * V_NUM;
  if (q < 30) {
    for (int v = tid; v < V_NUM; v += 256)
      part += jr[v] * SD[(size_t)v * 30 + q];
  } else {
    int cc = q - 30;
    for (int v = tid; v < V_NUM; v += 256)
      part += jr[v] * VT[(size_t)v * 3 + cc];
  }
  for (int off = 32; off > 0; off >>= 1) part += __shfl_down(part, off);
  __shared__ float sm[4];
  if ((tid & 63) == 0) sm[tid >> 6] = part;
  __syncthreads();
  if (tid == 0) {
    float s = sm[0] + sm[1] + sm[2] + sm[3];
    if (q < 30) JS[j * 30 + q] = s;
    else Jt[j * 3 + (q - 30)] = s;
  }
}

// ---------------- Kernel A2: convert A -> bf16 [MPAD][KP]  AND  W -> bf16 [VPAD][32] ----------------
__global__ __launch_bounds__(256) void k_conv(
    const float* __restrict__ SD, const float* __restrict__ PD,
    const float* __restrict__ W,
    unsigned short* __restrict__ Abf, unsigned short* __restrict__ Wbf) {
  int bid = blockIdx.x;
  int tid = threadIdx.x;
  if (bid < MPAD) {
    int m = bid, k = tid;
    float v = 0.f;
    if (m < M_DIM && k < KTOT)
      v = (k < 10) ? SD[(size_t)m * 10 + k] : PD[(size_t)m * 207 + (k - 10)];
    Abf[(size_t)m * KP + k] = f2bf(v);
  } else {
    int idx = (bid - MPAD) * 256 + tid;   // over VPAD*32 = 221184
    if (idx < VPAD * 32) {
      int v = idx >> 5, k = idx & 31;
      Wbf[idx] = (v < V_NUM && k < NJ) ? f2bf(W[(size_t)v * NJ + k]) : (unsigned short)0;
    }
  }
}

// ---------------- Kernel B: per-batch rodrigues + joints + kinematic chain ----------------
__global__ __launch_bounds__(64) void k_batch(
    const float* __restrict__ pose, const float* __restrict__ betas,
    const float* __restrict__ trans, const float* __restrict__ JS,
    const float* __restrict__ Jt, unsigned short* __restrict__ Kcb,
    unsigned short* __restrict__ GrelP, float* __restrict__ outG,
    float* __restrict__ outJtr, int B) {
  int b = blockIdx.x;
  int lane = threadIdx.x;
  __shared__ float rotS[NJ][9];
  __shared__ float jS[NJ * 3];
  __shared__ float Gs[NJ][12];
  __shared__ float GrS[NJ][12];

  if (lane < NJ) {
    float rx = pose[b * 72 + lane * 3 + 0];
    float ry = pose[b * 72 + lane * 3 + 1];
    float rz = pose[b * 72 + lane * 3 + 2];
    float a2 = rx * rx + ry * ry + rz * rz + 1e-16f;
    float ang = sqrtf(a2);
    float inv = 1.f / ang;
    float ux = rx * inv, uy = ry * inv, uz = rz * inv;
    float c = cosf(ang), s = sinf(ang), ic = 1.f - c;
    float R[9];
    R[0] = c + ic * ux * ux;      R[1] = ic * ux * uy - s * uz; R[2] = ic * ux * uz + s * uy;
    R[3] = ic * uy * ux + s * uz; R[4] = c + ic * uy * uy;      R[5] = ic * uy * uz - s * ux;
    R[6] = ic * uz * ux - s * uy; R[7] = ic * uz * uy + s * ux; R[8] = c + ic * uz * uz;
#pragma unroll
    for (int k = 0; k < 9; k++) rotS[lane][k] = R[k];
    if (lane > 0) {
#pragma unroll
      for (int k = 0; k < 9; k++) {
        float iden = (k == 0 || k == 4 || k == 8) ? 1.f : 0.f;
        Kcb[(size_t)b * KP + 10 + (lane - 1) * 9 + k] = f2bf(R[k] - iden);
      }
    }
  }
  if (lane < 10) Kcb[(size_t)b * KP + lane] = f2bf(betas[b * 10 + lane]);
  if (lane < KP - KTOT) Kcb[(size_t)b * KP + KTOT + lane] = 0;

  __syncthreads();
  for (int idx = lane; idx < 72; idx += 64) {
    float s = Jt[idx];
#pragma unroll
    for (int ss = 0; ss < 10; ss++) s += JS[idx * 10 + ss] * betas[b * 10 + ss];
    jS[idx] = s;
  }
  __syncthreads();

  if (lane == 0) {
#pragma unroll
    for (int p = 0; p < 3; p++) {
      Gs[0][p * 4 + 0] = rotS[0][p * 3 + 0];
      Gs[0][p * 4 + 1] = rotS[0][p * 3 + 1];
      Gs[0][p * 4 + 2] = rotS[0][p * 3 + 2];
      Gs[0][p * 4 + 3] = jS[p];
    }
    for (int i = 1; i < NJ; i++) {
      int par = c_parents[i];
      float t0 = jS[i * 3 + 0] - jS[par * 3 + 0];
      float t1 = jS[i * 3 + 1] - jS[par * 3 + 1];
      float t2 = jS[i * 3 + 2] - jS[par * 3 + 2];
#pragma unroll
      for (int p = 0; p < 3; p++) {
        float rp0 = Gs[par][p * 4 + 0], rp1 = Gs[par][p * 4 + 1], rp2 = Gs[par][p * 4 + 2];
#pragma unroll
        for (int q = 0; q < 3; q++) {
          Gs[i][p * 4 + q] = rp0 * rotS[i][0 * 3 + q] + rp1 * rotS[i][1 * 3 + q] + rp2 * rotS[i][2 * 3 + q];
        }
        Gs[i][p * 4 + 3] = rp0 * t0 + rp1 * t1 + rp2 * t2 + Gs[par][p * 4 + 3];
      }
    }
    for (int i = 0; i < NJ; i++) {
      float jx = jS[i * 3 + 0], jy = jS[i * 3 + 1], jz = jS[i * 3 + 2];
#pragma unroll
      for (int p = 0; p < 3; p++) {
        float g0 = Gs[i][p * 4 + 0], g1 = Gs[i][p * 4 + 1], g2 = Gs[i][p * 4 + 2];
        GrS[i][p * 4 + 0] = g0;
        GrS[i][p * 4 + 1] = g1;
        GrS[i][p * 4 + 2] = g2;
        GrS[i][p * 4 + 3] = Gs[i][p * 4 + 3] - (g0 * jx + g1 * jy + g2 * jz);
      }
    }
  }
  __syncthreads();

  for (int idx = lane; idx < NJ * 16; idx += 64) {
    int jj = idx >> 4, rc = idx & 15, p = rc >> 2, q = rc & 3;
    float val = (p < 3) ? Gs[jj][p * 4 + q] : ((q == 3) ? 1.f : 0.f);
    outG[(size_t)b * NJ * 16 + idx] = val;
  }
  for (int idx = lane; idx < NJ * 3; idx += 64) {
    int jj = idx / 3, p = idx % 3;
    outJtr[(size_t)b * NJ * 3 + idx] = Gs[jj][p * 4 + 3] + trans[b * 3 + p];
  }
  // GrelT bf16 panel: [c=0..15][j=0..39], zeros outside c<12, j<24
  for (int idx = lane; idx < 16 * 40; idx += 64) {
    int c = idx / 40, j = idx % 40;
    GrelP[(size_t)b * 640 + idx] = (c < 12 && j < NJ) ? f2bf(GrS[j][c]) : (unsigned short)0;
  }
}

// ---------------- Kernel C: MFMA GEMM, single 32KB buffer (5 blk/CU) + wave-private epilogue ----------------
__global__ __launch_bounds__(256) void k_pose_mfma(
    const unsigned short* __restrict__ Kcb, const unsigned short* __restrict__ Abf,
    const float* __restrict__ VT, float* __restrict__ outVP, int B) {
  __shared__ char ldsraw[32768];           // At(16K)+Bt(16K); epilogue reuses as 4x4352 wave slabs

  const int tid = threadIdx.x;
  const int lane = tid & 63;
  const int w = tid >> 6;
  const int wr = w >> 1, wc = w & 1;       // wr -> m half, wc -> b half
  const int b0 = blockIdx.y * 128;
  const int m0 = blockIdx.x * 128;

  // VT in reader layout: lane (a=lane&15, c=lane>>4) stores m = m0+wr*64+c*16+i*4+r
  f32x4 vt4[4];
  {
    int mbase = m0 + wr * 64 + ((lane >> 4) << 4);
#pragma unroll
    for (int i = 0; i < 4; i++) {
      int mm = mbase + i * 4;
      if (mm + 3 < M_DIM) vt4[i] = *(const f32x4*)(VT + mm);
      else {
#pragma unroll
        for (int r = 0; r < 4; r++) vt4[i][r] = (mm + r < M_DIM) ? VT[mm + r] : 0.f;
      }
    }
  }

  f32x4 acc[4][4];
#pragma unroll
  for (int i = 0; i < 4; i++)
#pragma unroll
    for (int j = 0; j < 4; j++) acc[i][j] = (f32x4){0.f, 0.f, 0.f, 0.f};

  int Lrow[4], Lkb[4];
#pragma unroll
  for (int i = 0; i < 4; i++) {
    int L = w * 4096 + i * 1024 + lane * 16;
    int row = L >> 7;
    int kb = (L & 127) ^ ((row & 7) << 4);
    Lrow[i] = row;
    Lkb[i] = kb >> 1;
  }

#pragma unroll
  for (int kt = 0; kt < 4; ++kt) {
    char* At = ldsraw;
    char* Bt = ldsraw + 16384;
#pragma unroll
    for (int i = 0; i < 4; i++) {
      const unsigned short* gA = Kcb + (size_t)(b0 + Lrow[i]) * KP + kt * 64 + Lkb[i];
      gl_lds16(gA, At + w * 4096 + i * 1024);
      const unsigned short* gB = Abf + (size_t)(m0 + Lrow[i]) * KP + kt * 64 + Lkb[i];
      gl_lds16(gB, Bt + w * 4096 + i * 1024);
    }
    __syncthreads();
#pragma unroll
    for (int h = 0; h < 2; ++h) {
      bf16x8 fm[4], fb[4];
#pragma unroll
      for (int fi = 0; fi < 4; fi++) {
        int row = wr * 64 + fi * 16 + (lane & 15);
        int byte = (row << 7) + ((h * 64 + ((lane >> 4) << 4)) ^ ((row & 7) << 4));
        fm[fi] = *(const bf16x8*)(Bt + byte);
      }
#pragma unroll
      for (int fj = 0; fj < 4; fj++) {
        int row = wc * 64 + fj * 16 + (lane & 15);
        int byte = (row << 7) + ((h * 64 + ((lane >> 4) << 4)) ^ ((row & 7) << 4));
        fb[fj] = *(const bf16x8*)(At + byte);
      }
#pragma unroll
      for (int fi = 0; fi < 4; fi++)
#pragma unroll
        for (int fj = 0; fj < 4; fj++)
          acc[fi][fj] = __builtin_amdgcn_mfma_f32_16x16x32_bf16(fm[fi], fb[fj], acc[fi][fj], 0, 0, 0);
    }
    __syncthreads();   // buffer reuse fence
  }

  // barrier-free wave-private epilogue
  char* wslab = ldsraw + w * 4352;          // 16 rows x 272 B
  const int a = lane & 15, c = lane >> 4;
  const int xr = (lane & 3) << 4;           // 16B-block XOR key (= a&3)
#pragma unroll
  for (int fj = 0; fj < 4; fj++) {
#pragma unroll
    for (int fi = 0; fi < 4; fi++) {
      int off = a * 272 + (((fi << 6) + (c << 4)) ^ xr);
      *(f32x4*)(wslab + off) = acc[fi][fj];
    }
    int brow = b0 + wc * 64 + fj * 16 + a;
    size_t gb = (size_t)brow * M_DIM;
    int mg0 = m0 + wr * 64 + (c << 4);
#pragma unroll
    for (int i = 0; i < 4; i++) {
      int off = a * 272 + (((c << 6) + (i << 4)) ^ xr);
      f32x4 v = *(f32x4*)(wslab + off);
      v = v + vt4[i];
      int mg = mg0 + i * 4;
      if (mg + 3 < M_DIM) {
        *(f32x4*)(outVP + gb + mg) = v;
      } else {
#pragma unroll
        for (int r = 0; r < 4; r++)
          if (mg + r < M_DIM) outVP[gb + mg + r] = v[r];
      }
    }
  }
}

// ---------------- Kernel D: MFMA skinning, b128 slot-swizzled T round-trip ----------------
// T slab per wave: [64 verts][16 dwords], slot = p ^ ((vi>>1)&3).
// Scatter: 4 x ds_write_b128 (contiguous 1KB per instr). Gather: 3 x ds_read_b128
// (8 bank-quads x 8 lanes = 8-cycle optimal). 7 b128 DS ops replace 28 b32.
__global__ __launch_bounds__(256) void k_skin9(
    const float* __restrict__ VP, const unsigned short* __restrict__ Wbf,
    const unsigned short* __restrict__ GrelP, const float* __restrict__ trans,
    float* __restrict__ outNK, float* __restrict__ outVerts, int B) {
  __shared__ float Tl[4][64 * 16];   // 16 KB
  const int tid = threadIdx.x;
  const int lane = tid & 63;
  const int w = tid >> 6;
  const int vl16 = lane & 15;
  const int p = lane >> 4;        // c-row group (3 = zero rows)
  const int kb = p * 8;           // k-base of this lane's fragment
  const int vbase = blockIdx.x * 256 + w * 64;
  const int b0 = blockIdx.y * 4;
  const int vg = vbase + lane;    // this lane's owned vert
  const bool vok = vg < V_NUM;
  const int kx = (lane >> 1) & 3; // gather slot key (vbase % 64 == 0)

  bf16x8 wf[4];
#pragma unroll
  for (int sub = 0; sub < 4; sub++)
    wf[sub] = *(const bf16x8*)(Wbf + (size_t)(vbase + sub * 16 + vl16) * 32 + kb);

  bf16x8 af[4];
#pragma unroll
  for (int bi = 0; bi < 4; bi++)
    af[bi] = *(const bf16x8*)(GrelP + (size_t)(b0 + bi) * 640 + vl16 * 40 + kb);

  float* myT = Tl[w];

  float xc0 = 0.f, xc1 = 0.f, xc2 = 0.f;
  if (vok) {
    const float* xp = VP + (size_t)b0 * M_DIM + (size_t)vg * 3;
    xc0 = xp[0]; xc1 = xp[1]; xc2 = xp[2];
  }

#pragma unroll
  for (int bi = 0; bi < 4; bi++) {
    int b = b0 + bi;
    f32x4 acc[4];
#pragma unroll
    for (int sub = 0; sub < 4; sub++) {
      f32x4 z = (f32x4){0.f, 0.f, 0.f, 0.f};
      acc[sub] = __builtin_amdgcn_mfma_f32_16x16x32_bf16(af[bi], wf[sub], z, 0, 0, 0);
    }
    // scatter: all lanes (incl p=3: zero rows) -> full slot coverage, conflict-free
#pragma unroll
    for (int sub = 0; sub < 4; sub++) {
      int vi = sub * 16 + vl16;
      int slot = p ^ ((vi >> 1) & 3);
      *(f32x4*)&myT[vi * 16 + slot * 4] = acc[sub];
    }
    // next x prefetch
    float xn0 = 0.f, xn1 = 0.f, xn2 = 0.f;
    if (bi < 3 && vok) {
      const float* xp = VP + (size_t)(b + 1) * M_DIM + (size_t)vg * 3;
      xn0 = xp[0]; xn1 = xp[1]; xn2 = xp[2];
    }
    if (vok) {
      // gather rows 0-3, 4-7, 8-11 from slots q^kx
      f32x4 ta = *(f32x4*)&myT[lane * 16 + ((0 ^ kx) << 2)];
      f32x4 tb = *(f32x4*)&myT[lane * 16 + ((1 ^ kx) << 2)];
      f32x4 tc = *(f32x4*)&myT[lane * 16 + ((2 ^ kx) << 2)];
      size_t base = (size_t)b * M_DIM + (size_t)vg * 3;
      float* onk = outNK + base;
      onk[0] = xc0; onk[1] = xc1; onk[2] = xc2;
      float* op = outVerts + base;
      op[0] = ta[0] * xc0 + ta[1] * xc1 + ta[2] * xc2 + ta[3] + trans[b * 3 + 0];
      op[1] = tb[0] * xc0 + tb[1] * xc1 + tb[2] * xc2 + tb[3] + trans[b * 3 + 1];
      op[2] = tc[0] * xc0 + tc[1] * xc1 + tc[2] * xc2 + tc[3] + trans[b * 3 + 2];
    }
    xc0 = xn0; xc1 = xn1; xc2 = xn2;
  }
}

extern "C" void kernel_launch(void* const* d_in, const int* in_sizes, int n_in,
                              void* d_out, int out_size, void* d_ws, size_t ws_size,
                              hipStream_t stream) {
  const float* pose  = (const float*)d_in[0];
  const float* betas = (const float*)d_in[1];
  const float* trans = (const float*)d_in[2];
  const float* vt    = (const float*)d_in[3];
  const float* sd    = (const float*)d_in[4];
  const float* pd    = (const float*)d_in[5];
  const float* jreg  = (const float*)d_in[6];
  const float* wgt   = (const float*)d_in[7];
  int B = in_sizes[0] / 72;

  float* out = (float*)d_out;
  size_t nvb = (size_t)B * M_DIM;
  float* o_verts = out;
  float* o_jtr   = o_verts + nvb;
  float* o_vp    = o_jtr + (size_t)B * NJ * 3;
  float* o_nk    = o_vp + nvb;
  float* o_G     = o_nk + nvb;

  char* wsb = (char*)d_ws;
  float* JS = (float*)wsb;                          // 720 f32
  float* Jt = JS + 720;                             // 72 f32
  size_t off = (720 + 72) * 4;                      // 3168 B (16-aligned)
  unsigned short* Kcb   = (unsigned short*)(wsb + off);                       // B*KP
  unsigned short* Abf   = (unsigned short*)(wsb + off + (size_t)B * KP * 2);  // MPAD*KP
  unsigned short* GrelP = Abf + (size_t)MPAD * KP;                            // B*640
  unsigned short* Wbf   = GrelP + (size_t)B * 640;                            // VPAD*32

  dim3 gR(24, 33);
  k_regress2<<<gR, 256, 0, stream>>>(jreg, sd, vt, JS, Jt);
  k_conv<<<MPAD + (VPAD * 32 + 255) / 256, 256, 0, stream>>>(sd, pd, wgt, Abf, Wbf);
  k_batch<<<B, 64, 0, stream>>>(pose, betas, trans, JS, Jt, Kcb, GrelP, o_G, o_jtr, B);
  dim3 gC(MPAD / 128, B / 128);
  k_pose_mfma<<<gC, 256, 0, stream>>>(Kcb, Abf, vt, o_vp, B);
  dim3 gD(VPAD / 256, B / 4);
  k_skin9<<<gD, 256, 0, stream>>>(o_vp, Wbf, GrelP, trans, o_nk, o_verts, B);
}